// Round 1
// baseline (506.305 us; speedup 1.0000x reference)
//
#include <hip/hip_runtime.h>

#define N_NODES 50000
#define N_EDGES 800000
#define FEAT    128
#define NOUT    128
#define SCAN_CHUNK 2048
#define NSCANBLK   ((N_NODES + SCAN_CHUNK - 1) / SCAN_CHUNK)   // 25

// ---------------- CSR build ----------------

__global__ void k_zero_int(int* __restrict__ p, int n) {
    int i = blockIdx.x * blockDim.x + threadIdx.x;
    if (i < n) p[i] = 0;
}

__global__ void k_count(const int* __restrict__ rows, int* __restrict__ cnt) {
    int e = blockIdx.x * blockDim.x + threadIdx.x;
    if (e < N_EDGES) atomicAdd(&cnt[rows[e]], 1);
}

// Per-block exclusive scan of counts (chunk = 2048), partial result into excl,
// block total into blksum.
__global__ void k_scan1(const int* __restrict__ cnt, int* __restrict__ excl,
                        int* __restrict__ blksum) {
    __shared__ int lds[256];
    const int t = threadIdx.x;
    const int base = blockIdx.x * SCAN_CHUNK + t * 8;
    int v[8], s = 0;
#pragma unroll
    for (int i = 0; i < 8; ++i) {
        int idx = base + i;
        v[i] = (idx < N_NODES) ? cnt[idx] : 0;
        s += v[i];
    }
    int val = s;
    lds[t] = val;
    __syncthreads();
#pragma unroll
    for (int off = 1; off < 256; off <<= 1) {
        int y = (t >= off) ? lds[t - off] : 0;
        __syncthreads();
        val += y;
        lds[t] = val;
        __syncthreads();
    }
    if (t == 255) blksum[blockIdx.x] = val;
    int run = val - s;   // exclusive prefix of this thread within block
#pragma unroll
    for (int i = 0; i < 8; ++i) {
        int idx = base + i;
        if (idx < N_NODES) excl[idx] = run;
        run += v[i];
    }
}

__global__ void k_scan2(int* __restrict__ blksum, int nb) {
    if (threadIdx.x == 0 && blockIdx.x == 0) {
        int run = 0;
        for (int i = 0; i < nb; ++i) { int v = blksum[i]; blksum[i] = run; run += v; }
    }
}

__global__ void k_scan3(int* __restrict__ row_ptr, const int* __restrict__ blksum,
                        int* __restrict__ row_fill) {
    int i = blockIdx.x * blockDim.x + threadIdx.x;
    if (i < N_NODES) {
        int v = row_ptr[i] + blksum[i / SCAN_CHUNK];
        row_ptr[i] = v;
        row_fill[i] = v;
    } else if (i == N_NODES) {
        row_ptr[N_NODES] = N_EDGES;
    }
}

__global__ void k_scatter(const int* __restrict__ rows, const int* __restrict__ cols,
                          const float* __restrict__ vals, int* __restrict__ row_fill,
                          int2* __restrict__ epairs) {
    int e = blockIdx.x * blockDim.x + threadIdx.x;
    if (e < N_EDGES) {
        int r = rows[e];
        int p = atomicAdd(&row_fill[r], 1);
        int2 pr;
        pr.x = cols[e];
        pr.y = __float_as_int(vals[e]);
        epairs[p] = pr;
    }
}

// ---------------- SpMM: one wave per row ----------------
// MODE 0: outbuf[r] = L@in [r]
// MODE 1: outbuf[r] = 2*(L@in)[r] - sub[r]   (outbuf may alias sub)

template <int MODE>
__global__ void k_spmm(const float* __restrict__ in, const int* __restrict__ row_ptr,
                       const int2* __restrict__ epairs, const float* __restrict__ sub,
                       float* __restrict__ outbuf) {
    const int r = blockIdx.x * 4 + (threadIdx.x >> 6);
    const int l2 = (threadIdx.x & 63) * 2;
    if (r >= N_NODES) return;
    const int beg = row_ptr[r], end = row_ptr[r + 1];
    float ax = 0.f, ay = 0.f;
    int j = beg;
    for (; j + 4 <= end; j += 4) {
        int2 p0 = epairs[j + 0];
        int2 p1 = epairs[j + 1];
        int2 p2 = epairs[j + 2];
        int2 p3 = epairs[j + 3];
        float2 g0 = *(const float2*)(in + p0.x * FEAT + l2);
        float2 g1 = *(const float2*)(in + p1.x * FEAT + l2);
        float2 g2 = *(const float2*)(in + p2.x * FEAT + l2);
        float2 g3 = *(const float2*)(in + p3.x * FEAT + l2);
        float v0 = __int_as_float(p0.y), v1 = __int_as_float(p1.y);
        float v2 = __int_as_float(p2.y), v3 = __int_as_float(p3.y);
        ax = fmaf(v0, g0.x, ax); ay = fmaf(v0, g0.y, ay);
        ax = fmaf(v1, g1.x, ax); ay = fmaf(v1, g1.y, ay);
        ax = fmaf(v2, g2.x, ax); ay = fmaf(v2, g2.y, ay);
        ax = fmaf(v3, g3.x, ax); ay = fmaf(v3, g3.y, ay);
    }
    for (; j < end; ++j) {
        int2 p0 = epairs[j];
        float2 g0 = *(const float2*)(in + p0.x * FEAT + l2);
        float v0 = __int_as_float(p0.y);
        ax = fmaf(v0, g0.x, ax); ay = fmaf(v0, g0.y, ay);
    }
    float* o = outbuf + (size_t)r * FEAT + l2;
    if (MODE == 0) {
        o[0] = ax; o[1] = ay;
    } else {
        const float* s = sub + (size_t)r * FEAT + l2;
        float s0 = s[0], s1 = s[1];
        o[0] = 2.f * ax - s0;
        o[1] = 2.f * ay - s1;
    }
}

// ---------------- GEMM-accumulate: out (+)= T @ Wk ----------------
// 128 threads/block, thread t owns output column o=t, W column in VGPRs.
// INIT=1: out = bias + T@Wk ; INIT=0: out += T@Wk

template <int INIT>
__global__ __launch_bounds__(128) void k_gemm(const float* __restrict__ T,
                                              const float* __restrict__ Wk,
                                              const float* __restrict__ bias,
                                              float* __restrict__ out) {
    const int o = threadIdx.x;
    float w[FEAT];
#pragma unroll
    for (int d = 0; d < FEAT; ++d) w[d] = Wk[d * NOUT + o];
    const float bo = INIT ? bias[o] : 0.f;
    for (int n = blockIdx.x; n < N_NODES; n += gridDim.x) {
        const float* __restrict__ tr = T + (size_t)n * FEAT;
        float a0 = 0.f, a1 = 0.f, a2 = 0.f, a3 = 0.f;
#pragma unroll
        for (int d = 0; d < FEAT; d += 4) {
            a0 = fmaf(tr[d + 0], w[d + 0], a0);
            a1 = fmaf(tr[d + 1], w[d + 1], a1);
            a2 = fmaf(tr[d + 2], w[d + 2], a2);
            a3 = fmaf(tr[d + 3], w[d + 3], a3);
        }
        float acc = (a0 + a1) + (a2 + a3);
        size_t oi = (size_t)n * NOUT + o;
        if (INIT) out[oi] = acc + bo;
        else      out[oi] += acc;
    }
}

// ---------------- launcher ----------------

extern "C" void kernel_launch(void* const* d_in, const int* in_sizes, int n_in,
                              void* d_out, int out_size, void* d_ws, size_t ws_size,
                              hipStream_t stream) {
    const float* x    = (const float*)d_in[0];
    const float* vals = (const float*)d_in[1];
    const float* W    = (const float*)d_in[2];
    const float* b    = (const float*)d_in[3];
    const int*   rows = (const int*)d_in[4];
    const int*   cols = (const int*)d_in[5];
    float* out = (float*)d_out;

    char* ws = (char*)d_ws;
    size_t off = 0;
    auto alloc = [&](size_t bytes) -> void* {
        void* p = ws + off;
        off = (off + bytes + 255) & ~(size_t)255;
        return p;
    };
    float* Ta      = (float*)alloc(sizeof(float) * (size_t)N_NODES * FEAT);
    float* Tb      = (float*)alloc(sizeof(float) * (size_t)N_NODES * FEAT);
    int*   row_ptr = (int*)alloc(sizeof(int) * (N_NODES + 1));
    int*   row_fill= (int*)alloc(sizeof(int) * N_NODES);
    int*   blksum  = (int*)alloc(sizeof(int) * 64);
    int2*  epairs  = (int2*)alloc(sizeof(int2) * (size_t)N_EDGES);

    // CSR build (counts go into row_fill, partial scan into row_ptr)
    k_zero_int<<<(N_NODES + 255) / 256, 256, 0, stream>>>(row_fill, N_NODES);
    k_count<<<(N_EDGES + 255) / 256, 256, 0, stream>>>(rows, row_fill);
    k_scan1<<<NSCANBLK, 256, 0, stream>>>(row_fill, row_ptr, blksum);
    k_scan2<<<1, 64, 0, stream>>>(blksum, NSCANBLK);
    k_scan3<<<(N_NODES + 256) / 256, 256, 0, stream>>>(row_ptr, blksum, row_fill);
    k_scatter<<<(N_EDGES + 255) / 256, 256, 0, stream>>>(rows, cols, vals, row_fill, epairs);

    // out = b + T0 @ W0   (T0 = x)
    k_gemm<1><<<1024, 128, 0, stream>>>(x, W + 0 * FEAT * NOUT, b, out);
    // T1 = L x  -> Tb
    k_spmm<0><<<N_NODES / 4, 256, 0, stream>>>(x, row_ptr, epairs, nullptr, Tb);
    // out += T1 @ W1
    k_gemm<0><<<1024, 128, 0, stream>>>(Tb, W + 1 * FEAT * NOUT, b, out);
    // T2 = 2 L T1 - x -> Ta
    k_spmm<1><<<N_NODES / 4, 256, 0, stream>>>(Tb, row_ptr, epairs, x, Ta);
    // out += T2 @ W2
    k_gemm<0><<<1024, 128, 0, stream>>>(Ta, W + 2 * FEAT * NOUT, b, out);
    // T3 = 2 L T2 - T1 -> Tb (in-place wrt sub: row r reads sub[r] then writes o[r])
    k_spmm<1><<<N_NODES / 4, 256, 0, stream>>>(Ta, row_ptr, epairs, Tb, Tb);
    // out += T3 @ W3
    k_gemm<0><<<1024, 128, 0, stream>>>(Tb, W + 3 * FEAT * NOUT, b, out);
}

// Round 2
// 323.484 us; speedup vs baseline: 1.5652x; 1.5652x over previous
//
#include <hip/hip_runtime.h>

#define N_NODES 50000
#define N_EDGES 800000
#define FEAT    128
#define NOUT    128
#define SCAN_CHUNK 2048
#define NSCANBLK   ((N_NODES + SCAN_CHUNK - 1) / SCAN_CHUNK)   // 25

typedef __attribute__((ext_vector_type(8))) short short8v;
typedef __attribute__((ext_vector_type(4))) float f32x4;

static __device__ __forceinline__ unsigned short f2bf(float f) {
    union { float f; unsigned int u; } c; c.f = f;
    unsigned int u = c.u;
    // round-to-nearest-even bf16 truncation
    return (unsigned short)((u + 0x7fffu + ((u >> 16) & 1u)) >> 16);
}

// ---------------- CSR build ----------------

__global__ void k_zero_int(int* __restrict__ p, int n) {
    int i = blockIdx.x * blockDim.x + threadIdx.x;
    if (i < n) p[i] = 0;
}

__global__ void k_count(const int* __restrict__ rows, int* __restrict__ cnt) {
    int e = blockIdx.x * blockDim.x + threadIdx.x;
    if (e < N_EDGES) atomicAdd(&cnt[rows[e]], 1);
}

__global__ void k_scan1(const int* __restrict__ cnt, int* __restrict__ excl,
                        int* __restrict__ blksum) {
    __shared__ int lds[256];
    const int t = threadIdx.x;
    const int base = blockIdx.x * SCAN_CHUNK + t * 8;
    int v[8], s = 0;
#pragma unroll
    for (int i = 0; i < 8; ++i) {
        int idx = base + i;
        v[i] = (idx < N_NODES) ? cnt[idx] : 0;
        s += v[i];
    }
    int val = s;
    lds[t] = val;
    __syncthreads();
#pragma unroll
    for (int off = 1; off < 256; off <<= 1) {
        int y = (t >= off) ? lds[t - off] : 0;
        __syncthreads();
        val += y;
        lds[t] = val;
        __syncthreads();
    }
    if (t == 255) blksum[blockIdx.x] = val;
    int run = val - s;
#pragma unroll
    for (int i = 0; i < 8; ++i) {
        int idx = base + i;
        if (idx < N_NODES) excl[idx] = run;
        run += v[i];
    }
}

__global__ void k_scan2(int* __restrict__ blksum, int nb) {
    if (threadIdx.x == 0 && blockIdx.x == 0) {
        int run = 0;
        for (int i = 0; i < nb; ++i) { int v = blksum[i]; blksum[i] = run; run += v; }
    }
}

__global__ void k_scan3(int* __restrict__ row_ptr, const int* __restrict__ blksum,
                        int* __restrict__ row_fill) {
    int i = blockIdx.x * blockDim.x + threadIdx.x;
    if (i < N_NODES) {
        int v = row_ptr[i] + blksum[i / SCAN_CHUNK];
        row_ptr[i] = v;
        row_fill[i] = v;
    } else if (i == N_NODES) {
        row_ptr[N_NODES] = N_EDGES;
    }
}

__global__ void k_scatter(const int* __restrict__ rows, const int* __restrict__ cols,
                          const float* __restrict__ vals, int* __restrict__ row_fill,
                          int2* __restrict__ epairs) {
    int e = blockIdx.x * blockDim.x + threadIdx.x;
    if (e < N_EDGES) {
        int r = rows[e];
        int p = atomicAdd(&row_fill[r], 1);
        int2 pr;
        pr.x = cols[e];
        pr.y = __float_as_int(vals[e]);
        epairs[p] = pr;
    }
}

// ---------------- SpMM: one wave per row (fp32 recurrence) ----------------
// MODE 0: outbuf[r] = (L@in)[r]
// MODE 1: outbuf[r] = 2*(L@in)[r] - sub[r]

template <int MODE>
__global__ void k_spmm(const float* __restrict__ in, const int* __restrict__ row_ptr,
                       const int2* __restrict__ epairs, const float* __restrict__ sub,
                       float* __restrict__ outbuf) {
    const int r = blockIdx.x * 4 + (threadIdx.x >> 6);
    const int l2 = (threadIdx.x & 63) * 2;
    if (r >= N_NODES) return;
    const int beg = row_ptr[r], end = row_ptr[r + 1];
    float ax = 0.f, ay = 0.f;
    int j = beg;
    for (; j + 4 <= end; j += 4) {
        int2 p0 = epairs[j + 0];
        int2 p1 = epairs[j + 1];
        int2 p2 = epairs[j + 2];
        int2 p3 = epairs[j + 3];
        float2 g0 = *(const float2*)(in + p0.x * FEAT + l2);
        float2 g1 = *(const float2*)(in + p1.x * FEAT + l2);
        float2 g2 = *(const float2*)(in + p2.x * FEAT + l2);
        float2 g3 = *(const float2*)(in + p3.x * FEAT + l2);
        float v0 = __int_as_float(p0.y), v1 = __int_as_float(p1.y);
        float v2 = __int_as_float(p2.y), v3 = __int_as_float(p3.y);
        ax = fmaf(v0, g0.x, ax); ay = fmaf(v0, g0.y, ay);
        ax = fmaf(v1, g1.x, ax); ay = fmaf(v1, g1.y, ay);
        ax = fmaf(v2, g2.x, ax); ay = fmaf(v2, g2.y, ay);
        ax = fmaf(v3, g3.x, ax); ay = fmaf(v3, g3.y, ay);
    }
    for (; j < end; ++j) {
        int2 p0 = epairs[j];
        float2 g0 = *(const float2*)(in + p0.x * FEAT + l2);
        float v0 = __int_as_float(p0.y);
        ax = fmaf(v0, g0.x, ax); ay = fmaf(v0, g0.y, ay);
    }
    float* o = outbuf + (size_t)r * FEAT + l2;
    if (MODE == 0) {
        o[0] = ax; o[1] = ay;
    } else {
        const float* s = sub + (size_t)r * FEAT + l2;
        float s0 = s[0], s1 = s[1];
        o[0] = 2.f * ax - s0;
        o[1] = 2.f * ay - s1;
    }
}

// ---------------- W prep: fp32 [512][128] -> bf16 fragment-ordered ----------------
// Layout: wf[((ct*16 + kk)*64 + lane)*8 + j] = bf16(W[k, col])
//   col = ct*16 + (lane&15), k = kk*32 + (lane>>4)*8 + j

__global__ void k_wprep(const float* __restrict__ W, unsigned short* __restrict__ wf) {
    int i = blockIdx.x * 256 + threadIdx.x;   // 8*16*64 = 8192
    if (i >= 8 * 16 * 64) return;
    int lane = i & 63;
    int kk = (i >> 6) & 15;
    int ct = i >> 10;
    int col = ct * 16 + (lane & 15);
    int k0 = kk * 32 + (lane >> 4) * 8;
    short8v o;
#pragma unroll
    for (int j = 0; j < 8; ++j)
        o[j] = (short)f2bf(W[(size_t)(k0 + j) * NOUT + col]);
    *(short8v*)(wf + (size_t)i * 8) = o;
}

// ---------------- Fused MFMA GEMM: out = [t0|t1|t2|t3] @ W + b ----------------
// Block: 256 threads (4 waves). Block tile: 64 rows x 64 cols (blockIdx.y half).
// Wave: 16 rows x 64 cols = 4 accum frags of 16x16, K=512 fully unrolled.

__global__ __launch_bounds__(256) void k_mfma_gemm(
    const float* __restrict__ t0, const float* __restrict__ t1,
    const float* __restrict__ t2, const float* __restrict__ t3,
    const unsigned short* __restrict__ wfrag,
    const float* __restrict__ bias, float* __restrict__ out)
{
    const int lane = threadIdx.x & 63;
    const int wid  = threadIdx.x >> 6;
    const int m0   = blockIdx.x * 64 + wid * 16;
    const int cb   = blockIdx.y;              // column half: 0 or 1
    const int arow = m0 + (lane & 15);
    const int kgrp = lane >> 4;               // 0..3

    f32x4 acc0 = {0.f, 0.f, 0.f, 0.f};
    f32x4 acc1 = {0.f, 0.f, 0.f, 0.f};
    f32x4 acc2 = {0.f, 0.f, 0.f, 0.f};
    f32x4 acc3 = {0.f, 0.f, 0.f, 0.f};

    const float* tp[4] = {t0, t1, t2, t3};
    const bool rowok = (arow < N_NODES);

#pragma unroll
    for (int kk = 0; kk < 16; ++kk) {
        const int term = kk >> 2;                 // constant after unroll
        const float* ap = tp[term];
        short8v afrag;
        if (rowok) {
            const float* a = ap + (size_t)arow * FEAT + (kk & 3) * 32 + kgrp * 8;
            float4 f0 = *(const float4*)(a);
            float4 f1 = *(const float4*)(a + 4);
            afrag[0] = (short)f2bf(f0.x);
            afrag[1] = (short)f2bf(f0.y);
            afrag[2] = (short)f2bf(f0.z);
            afrag[3] = (short)f2bf(f0.w);
            afrag[4] = (short)f2bf(f1.x);
            afrag[5] = (short)f2bf(f1.y);
            afrag[6] = (short)f2bf(f1.z);
            afrag[7] = (short)f2bf(f1.w);
        } else {
            afrag = (short8v)0;
        }
        const unsigned short* wb =
            wfrag + ((size_t)((cb * 4 + 0) * 16 + kk) * 64 + lane) * 8;
        // 4 col-tiles: strides of 16*64*8 shorts between tiles
        short8v b0 = *(const short8v*)(wb);
        short8v b1 = *(const short8v*)(wb + 16 * 64 * 8);
        short8v b2 = *(const short8v*)(wb + 2 * 16 * 64 * 8);
        short8v b3 = *(const short8v*)(wb + 3 * 16 * 64 * 8);
        acc0 = __builtin_amdgcn_mfma_f32_16x16x32_bf16(afrag, b0, acc0, 0, 0, 0);
        acc1 = __builtin_amdgcn_mfma_f32_16x16x32_bf16(afrag, b1, acc1, 0, 0, 0);
        acc2 = __builtin_amdgcn_mfma_f32_16x16x32_bf16(afrag, b2, acc2, 0, 0, 0);
        acc3 = __builtin_amdgcn_mfma_f32_16x16x32_bf16(afrag, b3, acc3, 0, 0, 0);
    }

    // epilogue: C/D layout col=lane&15, row=kgrp*4+i
#pragma unroll
    for (int t = 0; t < 4; ++t) {
        f32x4 acc = (t == 0) ? acc0 : (t == 1) ? acc1 : (t == 2) ? acc2 : acc3;
        int col = cb * 64 + t * 16 + (lane & 15);
        float bv = bias[col];
#pragma unroll
        for (int i = 0; i < 4; ++i) {
            int row = m0 + kgrp * 4 + i;
            if (row < N_NODES) out[(size_t)row * NOUT + col] = acc[i] + bv;
        }
    }
}

// ---------------- launcher ----------------

extern "C" void kernel_launch(void* const* d_in, const int* in_sizes, int n_in,
                              void* d_out, int out_size, void* d_ws, size_t ws_size,
                              hipStream_t stream) {
    const float* x    = (const float*)d_in[0];
    const float* vals = (const float*)d_in[1];
    const float* W    = (const float*)d_in[2];
    const float* b    = (const float*)d_in[3];
    const int*   rows = (const int*)d_in[4];
    const int*   cols = (const int*)d_in[5];
    float* out = (float*)d_out;

    char* ws = (char*)d_ws;
    size_t off = 0;
    auto alloc = [&](size_t bytes) -> void* {
        void* p = ws + off;
        off = (off + bytes + 255) & ~(size_t)255;
        return p;
    };
    float* T1      = (float*)alloc(sizeof(float) * (size_t)N_NODES * FEAT);
    float* T2      = (float*)alloc(sizeof(float) * (size_t)N_NODES * FEAT);
    float* T3      = (float*)alloc(sizeof(float) * (size_t)N_NODES * FEAT);
    int*   row_ptr = (int*)alloc(sizeof(int) * (N_NODES + 1));
    int*   row_fill= (int*)alloc(sizeof(int) * N_NODES);
    int*   blksum  = (int*)alloc(sizeof(int) * 64);
    int2*  epairs  = (int2*)alloc(sizeof(int2) * (size_t)N_EDGES);
    unsigned short* wfrag = (unsigned short*)alloc(sizeof(unsigned short) * 8 * 16 * 64 * 8);

    // CSR build
    k_zero_int<<<(N_NODES + 255) / 256, 256, 0, stream>>>(row_fill, N_NODES);
    k_count<<<(N_EDGES + 255) / 256, 256, 0, stream>>>(rows, row_fill);
    k_scan1<<<NSCANBLK, 256, 0, stream>>>(row_fill, row_ptr, blksum);
    k_scan2<<<1, 64, 0, stream>>>(blksum, NSCANBLK);
    k_scan3<<<(N_NODES + 256) / 256, 256, 0, stream>>>(row_ptr, blksum, row_fill);
    k_scatter<<<(N_EDGES + 255) / 256, 256, 0, stream>>>(rows, cols, vals, row_fill, epairs);

    // W -> bf16 fragment layout (independent of CSR/SpMM; scheduled early)
    k_wprep<<<32, 256, 0, stream>>>(W, wfrag);

    // Chebyshev recurrence in fp32
    k_spmm<0><<<N_NODES / 4, 256, 0, stream>>>(x,  row_ptr, epairs, nullptr, T1);
    k_spmm<1><<<N_NODES / 4, 256, 0, stream>>>(T1, row_ptr, epairs, x,       T2);
    k_spmm<1><<<N_NODES / 4, 256, 0, stream>>>(T2, row_ptr, epairs, T1,      T3);

    // One fused MFMA GEMM: out = [x|T1|T2|T3] @ W + b
    dim3 grid((N_NODES + 63) / 64, 2);
    k_mfma_gemm<<<grid, 256, 0, stream>>>(x, T1, T2, T3, wfrag, b, out);
}

// Round 3
// 265.409 us; speedup vs baseline: 1.9076x; 1.2188x over previous
//
#include <hip/hip_runtime.h>

#define N_NODES 50000
#define N_EDGES 800000
#define FEAT    128
#define NOUT    128
#define SCAN_CHUNK 2048
#define NSCANBLK   ((N_NODES + SCAN_CHUNK - 1) / SCAN_CHUNK)   // 25

typedef __attribute__((ext_vector_type(8))) short short8v;
typedef __attribute__((ext_vector_type(4))) float f32x4;
typedef unsigned short ushort_t;

static __device__ __forceinline__ unsigned short f2bf(float f) {
    union { float f; unsigned int u; } c; c.f = f;
    unsigned int u = c.u;
    return (unsigned short)((u + 0x7fffu + ((u >> 16) & 1u)) >> 16);
}
static __device__ __forceinline__ float bf_lo(unsigned int u) {
    return __uint_as_float(u << 16);
}
static __device__ __forceinline__ float bf_hi(unsigned int u) {
    return __uint_as_float(u & 0xffff0000u);
}

// ---------------- CSR build ----------------

__global__ void k_zero_int(int* __restrict__ p, int n) {
    int i = blockIdx.x * blockDim.x + threadIdx.x;
    if (i < n) p[i] = 0;
}

__global__ void k_count(const int* __restrict__ rows, int* __restrict__ cnt) {
    int e = blockIdx.x * blockDim.x + threadIdx.x;
    if (e < N_EDGES) atomicAdd(&cnt[rows[e]], 1);
}

__global__ void k_scan1(const int* __restrict__ cnt, int* __restrict__ excl,
                        int* __restrict__ blksum) {
    __shared__ int lds[256];
    const int t = threadIdx.x;
    const int base = blockIdx.x * SCAN_CHUNK + t * 8;
    int v[8], s = 0;
#pragma unroll
    for (int i = 0; i < 8; ++i) {
        int idx = base + i;
        v[i] = (idx < N_NODES) ? cnt[idx] : 0;
        s += v[i];
    }
    int val = s;
    lds[t] = val;
    __syncthreads();
#pragma unroll
    for (int off = 1; off < 256; off <<= 1) {
        int y = (t >= off) ? lds[t - off] : 0;
        __syncthreads();
        val += y;
        lds[t] = val;
        __syncthreads();
    }
    if (t == 255) blksum[blockIdx.x] = val;
    int run = val - s;
#pragma unroll
    for (int i = 0; i < 8; ++i) {
        int idx = base + i;
        if (idx < N_NODES) excl[idx] = run;
        run += v[i];
    }
}

__global__ void k_scan2(int* __restrict__ blksum, int nb) {
    if (threadIdx.x == 0 && blockIdx.x == 0) {
        int run = 0;
        for (int i = 0; i < nb; ++i) { int v = blksum[i]; blksum[i] = run; run += v; }
    }
}

__global__ void k_scan3(int* __restrict__ row_ptr, const int* __restrict__ blksum,
                        int* __restrict__ row_fill) {
    int i = blockIdx.x * blockDim.x + threadIdx.x;
    if (i < N_NODES) {
        int v = row_ptr[i] + blksum[i / SCAN_CHUNK];
        row_ptr[i] = v;
        row_fill[i] = v;
    } else if (i == N_NODES) {
        row_ptr[N_NODES] = N_EDGES;
    }
}

__global__ void k_scatter(const int* __restrict__ rows, const int* __restrict__ cols,
                          const float* __restrict__ vals, int* __restrict__ row_fill,
                          int2* __restrict__ epairs) {
    int e = blockIdx.x * blockDim.x + threadIdx.x;
    if (e < N_EDGES) {
        int r = rows[e];
        int p = atomicAdd(&row_fill[r], 1);
        int2 pr;
        pr.x = cols[e];
        pr.y = __float_as_int(vals[e]);
        epairs[p] = pr;
    }
}

// ---------------- x -> bf16 copy ----------------

__global__ void k_xconv(const float* __restrict__ x, ushort_t* __restrict__ xb) {
    int i = blockIdx.x * blockDim.x + threadIdx.x;   // over 6.4M/4 = 1.6M
    if (i >= N_NODES * FEAT / 4) return;
    float4 f = *(const float4*)(x + (size_t)i * 4);
    ushort_t o[4] = {f2bf(f.x), f2bf(f.y), f2bf(f.z), f2bf(f.w)};
    *(ushort2*)(xb + (size_t)i * 4)     = *(ushort2*)&o[0];
    *(ushort2*)(xb + (size_t)i * 4 + 2) = *(ushort2*)&o[2];
}

// ---------------- SpMM (bf16 storage, fp32 accumulate) ----------------
// MODE 0: outbuf[r] = (L@in)[r]
// MODE 1: outbuf[r] = 2*(L@in)[r] - sub[r]
// One wave per row; lane handles features [2*lane, 2*lane+1] (one uint per row).

template <int MODE>
__global__ void k_spmm(const ushort_t* __restrict__ in, const int* __restrict__ row_ptr,
                       const int2* __restrict__ epairs, const ushort_t* __restrict__ sub,
                       ushort_t* __restrict__ outbuf) {
    const int r = blockIdx.x * 4 + (threadIdx.x >> 6);
    const int l2 = (threadIdx.x & 63) * 2;
    if (r >= N_NODES) return;
    const int beg = row_ptr[r], end = row_ptr[r + 1];
    float ax = 0.f, ay = 0.f;
    int j = beg;
    for (; j + 8 <= end; j += 8) {
#pragma unroll
        for (int q = 0; q < 8; ++q) {
            int2 p = epairs[j + q];
            unsigned int u = *(const unsigned int*)(in + (size_t)p.x * FEAT + l2);
            float v = __int_as_float(p.y);
            ax = fmaf(v, bf_lo(u), ax);
            ay = fmaf(v, bf_hi(u), ay);
        }
    }
    for (; j < end; ++j) {
        int2 p = epairs[j];
        unsigned int u = *(const unsigned int*)(in + (size_t)p.x * FEAT + l2);
        float v = __int_as_float(p.y);
        ax = fmaf(v, bf_lo(u), ax);
        ay = fmaf(v, bf_hi(u), ay);
    }
    if (MODE == 1) {
        unsigned int su = *(const unsigned int*)(sub + (size_t)r * FEAT + l2);
        ax = 2.f * ax - bf_lo(su);
        ay = 2.f * ay - bf_hi(su);
    }
    unsigned int o = (unsigned int)f2bf(ax) | ((unsigned int)f2bf(ay) << 16);
    *(unsigned int*)(outbuf + (size_t)r * FEAT + l2) = o;
}

// ---------------- W prep: fp32 [512][128] -> bf16 fragment-ordered ----------------
// wf[((ct*16 + kk)*64 + lane)*8 + j] = bf16(W[k, col])
//   col = ct*16 + (lane&15), k = kk*32 + (lane>>4)*8 + j

__global__ void k_wprep(const float* __restrict__ W, ushort_t* __restrict__ wf) {
    int i = blockIdx.x * 256 + threadIdx.x;   // 8*16*64 = 8192
    if (i >= 8 * 16 * 64) return;
    int lane = i & 63;
    int kk = (i >> 6) & 15;
    int ct = i >> 10;
    int col = ct * 16 + (lane & 15);
    int k0 = kk * 32 + (lane >> 4) * 8;
    short8v o;
#pragma unroll
    for (int j = 0; j < 8; ++j)
        o[j] = (short)f2bf(W[(size_t)(k0 + j) * NOUT + col]);
    *(short8v*)(wf + (size_t)i * 8) = o;
}

// ---------------- Fused MFMA GEMM: out = [xb|T1|T2|T3] @ W + b ----------------
// Block: 256 threads (4 waves); tile 64 rows x 64 cols (blockIdx.y = col half).
// A operands read directly as bf16 short8v from the recurrence buffers.

__global__ __launch_bounds__(256) void k_mfma_gemm(
    const ushort_t* __restrict__ t0, const ushort_t* __restrict__ t1,
    const ushort_t* __restrict__ t2, const ushort_t* __restrict__ t3,
    const ushort_t* __restrict__ wfrag,
    const float* __restrict__ bias, float* __restrict__ out)
{
    const int lane = threadIdx.x & 63;
    const int wid  = threadIdx.x >> 6;
    const int m0   = blockIdx.x * 64 + wid * 16;
    const int cb   = blockIdx.y;
    const int arow = m0 + (lane & 15);
    const int kgrp = lane >> 4;

    f32x4 acc0 = {0.f, 0.f, 0.f, 0.f};
    f32x4 acc1 = {0.f, 0.f, 0.f, 0.f};
    f32x4 acc2 = {0.f, 0.f, 0.f, 0.f};
    f32x4 acc3 = {0.f, 0.f, 0.f, 0.f};

    const ushort_t* tp[4] = {t0, t1, t2, t3};
    const bool rowok = (arow < N_NODES);

#pragma unroll
    for (int kk = 0; kk < 16; ++kk) {
        const int term = kk >> 2;
        const ushort_t* ap = tp[term];
        short8v afrag;
        if (rowok) {
            afrag = *(const short8v*)(ap + (size_t)arow * FEAT + (kk & 3) * 32 + kgrp * 8);
        } else {
            afrag = (short8v)0;
        }
        const ushort_t* wb =
            wfrag + ((size_t)((cb * 4 + 0) * 16 + kk) * 64 + lane) * 8;
        short8v b0 = *(const short8v*)(wb);
        short8v b1 = *(const short8v*)(wb + 16 * 64 * 8);
        short8v b2 = *(const short8v*)(wb + 2 * 16 * 64 * 8);
        short8v b3 = *(const short8v*)(wb + 3 * 16 * 64 * 8);
        acc0 = __builtin_amdgcn_mfma_f32_16x16x32_bf16(afrag, b0, acc0, 0, 0, 0);
        acc1 = __builtin_amdgcn_mfma_f32_16x16x32_bf16(afrag, b1, acc1, 0, 0, 0);
        acc2 = __builtin_amdgcn_mfma_f32_16x16x32_bf16(afrag, b2, acc2, 0, 0, 0);
        acc3 = __builtin_amdgcn_mfma_f32_16x16x32_bf16(afrag, b3, acc3, 0, 0, 0);
    }

#pragma unroll
    for (int t = 0; t < 4; ++t) {
        f32x4 acc = (t == 0) ? acc0 : (t == 1) ? acc1 : (t == 2) ? acc2 : acc3;
        int col = cb * 64 + t * 16 + (lane & 15);
        float bv = bias[col];
#pragma unroll
        for (int i = 0; i < 4; ++i) {
            int row = m0 + kgrp * 4 + i;
            if (row < N_NODES) out[(size_t)row * NOUT + col] = acc[i] + bv;
        }
    }
}

// ---------------- launcher ----------------

extern "C" void kernel_launch(void* const* d_in, const int* in_sizes, int n_in,
                              void* d_out, int out_size, void* d_ws, size_t ws_size,
                              hipStream_t stream) {
    const float* x    = (const float*)d_in[0];
    const float* vals = (const float*)d_in[1];
    const float* W    = (const float*)d_in[2];
    const float* b    = (const float*)d_in[3];
    const int*   rows = (const int*)d_in[4];
    const int*   cols = (const int*)d_in[5];
    float* out = (float*)d_out;

    char* ws = (char*)d_ws;
    size_t off = 0;
    auto alloc = [&](size_t bytes) -> void* {
        void* p = ws + off;
        off = (off + bytes + 255) & ~(size_t)255;
        return p;
    };
    ushort_t* Xb   = (ushort_t*)alloc(sizeof(ushort_t) * (size_t)N_NODES * FEAT);
    ushort_t* T1   = (ushort_t*)alloc(sizeof(ushort_t) * (size_t)N_NODES * FEAT);
    ushort_t* T2   = (ushort_t*)alloc(sizeof(ushort_t) * (size_t)N_NODES * FEAT);
    ushort_t* T3   = (ushort_t*)alloc(sizeof(ushort_t) * (size_t)N_NODES * FEAT);
    int*   row_ptr = (int*)alloc(sizeof(int) * (N_NODES + 1));
    int*   row_fill= (int*)alloc(sizeof(int) * N_NODES);
    int*   blksum  = (int*)alloc(sizeof(int) * 64);
    int2*  epairs  = (int2*)alloc(sizeof(int2) * (size_t)N_EDGES);
    ushort_t* wfrag = (ushort_t*)alloc(sizeof(ushort_t) * 8 * 16 * 64 * 8);

    // CSR build
    k_zero_int<<<(N_NODES + 255) / 256, 256, 0, stream>>>(row_fill, N_NODES);
    k_count<<<(N_EDGES + 255) / 256, 256, 0, stream>>>(rows, row_fill);
    k_scan1<<<NSCANBLK, 256, 0, stream>>>(row_fill, row_ptr, blksum);
    k_scan2<<<1, 64, 0, stream>>>(blksum, NSCANBLK);
    k_scan3<<<(N_NODES + 256) / 256, 256, 0, stream>>>(row_ptr, blksum, row_fill);
    k_scatter<<<(N_EDGES + 255) / 256, 256, 0, stream>>>(rows, cols, vals, row_fill, epairs);

    // dense-side prep
    k_xconv<<<(N_NODES * FEAT / 4 + 255) / 256, 256, 0, stream>>>(x, Xb);
    k_wprep<<<32, 256, 0, stream>>>(W, wfrag);

    // Chebyshev recurrence (bf16 storage, fp32 accumulate)
    k_spmm<0><<<N_NODES / 4, 256, 0, stream>>>(Xb, row_ptr, epairs, nullptr, T1);
    k_spmm<1><<<N_NODES / 4, 256, 0, stream>>>(T1, row_ptr, epairs, Xb, T2);
    k_spmm<1><<<N_NODES / 4, 256, 0, stream>>>(T2, row_ptr, epairs, T1, T3);

    // One fused MFMA GEMM: out = [Xb|T1|T2|T3] @ W + b
    dim3 grid((N_NODES + 63) / 64, 2);
    k_mfma_gemm<<<grid, 256, 0, stream>>>(Xb, T1, T2, T3, wfrag, b, out);
}

// Round 4
// 211.699 us; speedup vs baseline: 2.3916x; 1.2537x over previous
//
#include <hip/hip_runtime.h>

#define N_NODES 50000
#define N_EDGES 800000
#define FEAT    128
#define NOUT    128
#define NBUCK   196                      // ceil(50000/256)
#define NTILE   ((N_EDGES + 2047) / 2048)  // 391 phase-A blocks

typedef __attribute__((ext_vector_type(8))) short short8v;
typedef __attribute__((ext_vector_type(4))) float f32x4;
typedef unsigned short ushort_t;

static __device__ __forceinline__ unsigned short f2bf(float f) {
    union { float f; unsigned int u; } c; c.f = f;
    unsigned int u = c.u;
    return (unsigned short)((u + 0x7fffu + ((u >> 16) & 1u)) >> 16);
}
static __device__ __forceinline__ float bf_lo(unsigned int u) {
    return __uint_as_float(u << 16);
}
static __device__ __forceinline__ float bf_hi(unsigned int u) {
    return __uint_as_float(u & 0xffff0000u);
}

// ---------------- bucketed CSR build ----------------

__global__ void k_zero_int(int* __restrict__ p, int n) {
    int i = blockIdx.x * blockDim.x + threadIdx.x;
    if (i < n) p[i] = 0;
}

// bucket histogram (LDS-aggregated)
__global__ __launch_bounds__(256) void k_bhist(const int* __restrict__ rows,
                                               int* __restrict__ gcnt) {
    __shared__ int h[NBUCK];
    for (int i = threadIdx.x; i < NBUCK; i += 256) h[i] = 0;
    __syncthreads();
    const int base = blockIdx.x * 2048;
#pragma unroll
    for (int k = 0; k < 8; ++k) {
        int e = base + k * 256 + threadIdx.x;
        if (e < N_EDGES) atomicAdd(&h[rows[e] >> 8], 1);
    }
    __syncthreads();
    for (int i = threadIdx.x; i < NBUCK; i += 256)
        if (h[i]) atomicAdd(&gcnt[i], h[i]);
}

// tiny exclusive scan over 196 buckets
__global__ void k_bscan(const int* __restrict__ gcnt, int* __restrict__ bbase,
                        int* __restrict__ gfill) {
    if (threadIdx.x == 0 && blockIdx.x == 0) {
        int run = 0;
        for (int i = 0; i < NBUCK; ++i) {
            bbase[i] = run; gfill[i] = run; run += gcnt[i];
        }
        bbase[NBUCK] = run;   // == N_EDGES
    }
}

// Phase A: bucketed append with LDS tile aggregation.
// bpairs[p].x = (row&255)<<16 | col ; .y = val bits
__global__ __launch_bounds__(256) void k_bucketA(
    const int* __restrict__ rows, const int* __restrict__ cols,
    const float* __restrict__ vals, int* __restrict__ gfill,
    int2* __restrict__ bpairs)
{
    __shared__ int h[NBUCK];
    __shared__ int off[NBUCK];
    __shared__ int cb[NBUCK];
    for (int i = threadIdx.x; i < NBUCK; i += 256) { h[i] = 0; off[i] = 0; }
    __syncthreads();
    const int base = blockIdx.x * 2048;
    int enc[8];
#pragma unroll
    for (int k = 0; k < 8; ++k) {
        int e = base + k * 256 + threadIdx.x;
        enc[k] = -1;
        if (e < N_EDGES) {
            int r = rows[e];
            enc[k] = (r >> 8) | ((r & 255) << 16);
            atomicAdd(&h[r >> 8], 1);
        }
    }
    __syncthreads();
    for (int i = threadIdx.x; i < NBUCK; i += 256)
        cb[i] = h[i] ? atomicAdd(&gfill[i], h[i]) : 0;
    __syncthreads();
#pragma unroll
    for (int k = 0; k < 8; ++k) {
        int e = base + k * 256 + threadIdx.x;
        if (e >= N_EDGES) continue;
        int bk = enc[k] & 0xffff;
        int rowlo = enc[k] >> 16;
        int p = cb[bk] + atomicAdd(&off[bk], 1);
        int2 pr;
        pr.x = (rowlo << 16) | cols[e];
        pr.y = __float_as_int(vals[e]);
        bpairs[p] = pr;
    }
}

// Phase B: per-bucket row histogram + scan -> row_ptr, then local ordered scatter.
__global__ __launch_bounds__(256) void k_bucketB(
    const int* __restrict__ bbase, const int2* __restrict__ bpairs,
    int* __restrict__ row_ptr, int2* __restrict__ epairs)
{
    __shared__ int hist[256];
    __shared__ int scan[256];
    __shared__ int fill[256];
    const int b = blockIdx.x;
    const int t = threadIdx.x;
    const int beg = bbase[b], end = bbase[b + 1];
    hist[t] = 0;
    __syncthreads();
    for (int j = beg + t; j < end; j += 256)
        atomicAdd(&hist[bpairs[j].x >> 16], 1);
    __syncthreads();
    int orig = hist[t];
    int val = orig;
    scan[t] = val;
    __syncthreads();
#pragma unroll
    for (int o = 1; o < 256; o <<= 1) {
        int y = (t >= o) ? scan[t - o] : 0;
        __syncthreads();
        val += y;
        scan[t] = val;
        __syncthreads();
    }
    const int rp = beg + (val - orig);      // exclusive prefix + bucket base
    const int gr = b * 256 + t;
    if (gr <= N_NODES) row_ptr[gr] = rp;    // b=195,t=80 writes row_ptr[N]=E
    fill[t] = rp;
    __syncthreads();
    for (int j = beg + t; j < end; j += 256) {
        int2 pk = bpairs[j];
        int rowlo = pk.x >> 16;
        int p = atomicAdd(&fill[rowlo], 1);
        int2 pr;
        pr.x = pk.x & 0xffff;
        pr.y = pk.y;
        epairs[p] = pr;
    }
}

// ---------------- x -> bf16 copy ----------------

__global__ void k_xconv(const float* __restrict__ x, ushort_t* __restrict__ xb) {
    int i = blockIdx.x * blockDim.x + threadIdx.x;
    if (i >= N_NODES * FEAT / 4) return;
    float4 f = *(const float4*)(x + (size_t)i * 4);
    ushort_t o[4] = {f2bf(f.x), f2bf(f.y), f2bf(f.z), f2bf(f.w)};
    *(ushort2*)(xb + (size_t)i * 4)     = *(ushort2*)&o[0];
    *(ushort2*)(xb + (size_t)i * 4 + 2) = *(ushort2*)&o[2];
}

// ---------------- SpMM (bf16 storage, fp32 accumulate) ----------------

template <int MODE>
__global__ void k_spmm(const ushort_t* __restrict__ in, const int* __restrict__ row_ptr,
                       const int2* __restrict__ epairs, const ushort_t* __restrict__ sub,
                       ushort_t* __restrict__ outbuf) {
    const int r = blockIdx.x * 4 + (threadIdx.x >> 6);
    const int l2 = (threadIdx.x & 63) * 2;
    if (r >= N_NODES) return;
    const int beg = row_ptr[r], end = row_ptr[r + 1];
    float ax = 0.f, ay = 0.f;
    int j = beg;
    for (; j + 8 <= end; j += 8) {
#pragma unroll
        for (int q = 0; q < 8; ++q) {
            int2 p = epairs[j + q];
            unsigned int u = *(const unsigned int*)(in + (size_t)p.x * FEAT + l2);
            float v = __int_as_float(p.y);
            ax = fmaf(v, bf_lo(u), ax);
            ay = fmaf(v, bf_hi(u), ay);
        }
    }
    for (; j < end; ++j) {
        int2 p = epairs[j];
        unsigned int u = *(const unsigned int*)(in + (size_t)p.x * FEAT + l2);
        float v = __int_as_float(p.y);
        ax = fmaf(v, bf_lo(u), ax);
        ay = fmaf(v, bf_hi(u), ay);
    }
    if (MODE == 1) {
        unsigned int su = *(const unsigned int*)(sub + (size_t)r * FEAT + l2);
        ax = 2.f * ax - bf_lo(su);
        ay = 2.f * ay - bf_hi(su);
    }
    unsigned int o = (unsigned int)f2bf(ax) | ((unsigned int)f2bf(ay) << 16);
    *(unsigned int*)(outbuf + (size_t)r * FEAT + l2) = o;
}

// ---------------- W prep: fp32 [512][128] -> bf16 fragment-ordered ----------------

__global__ void k_wprep(const float* __restrict__ W, ushort_t* __restrict__ wf) {
    int i = blockIdx.x * 256 + threadIdx.x;   // 8*16*64 = 8192
    if (i >= 8 * 16 * 64) return;
    int lane = i & 63;
    int kk = (i >> 6) & 15;
    int ct = i >> 10;
    int col = ct * 16 + (lane & 15);
    int k0 = kk * 32 + (lane >> 4) * 8;
    short8v o;
#pragma unroll
    for (int j = 0; j < 8; ++j)
        o[j] = (short)f2bf(W[(size_t)(k0 + j) * NOUT + col]);
    *(short8v*)(wf + (size_t)i * 8) = o;
}

// ---------------- Fused MFMA GEMM: out = [xb|T1|T2|T3] @ W + b ----------------

__global__ __launch_bounds__(256) void k_mfma_gemm(
    const ushort_t* __restrict__ t0, const ushort_t* __restrict__ t1,
    const ushort_t* __restrict__ t2, const ushort_t* __restrict__ t3,
    const ushort_t* __restrict__ wfrag,
    const float* __restrict__ bias, float* __restrict__ out)
{
    const int lane = threadIdx.x & 63;
    const int wid  = threadIdx.x >> 6;
    const int m0   = blockIdx.x * 64 + wid * 16;
    const int cb   = blockIdx.y;
    const int arow = m0 + (lane & 15);
    const int kgrp = lane >> 4;

    f32x4 acc0 = {0.f, 0.f, 0.f, 0.f};
    f32x4 acc1 = {0.f, 0.f, 0.f, 0.f};
    f32x4 acc2 = {0.f, 0.f, 0.f, 0.f};
    f32x4 acc3 = {0.f, 0.f, 0.f, 0.f};

    const ushort_t* tp[4] = {t0, t1, t2, t3};
    const bool rowok = (arow < N_NODES);

#pragma unroll
    for (int kk = 0; kk < 16; ++kk) {
        const int term = kk >> 2;
        const ushort_t* ap = tp[term];
        short8v afrag;
        if (rowok) {
            afrag = *(const short8v*)(ap + (size_t)arow * FEAT + (kk & 3) * 32 + kgrp * 8);
        } else {
            afrag = (short8v)0;
        }
        const ushort_t* wb =
            wfrag + ((size_t)((cb * 4 + 0) * 16 + kk) * 64 + lane) * 8;
        short8v b0 = *(const short8v*)(wb);
        short8v b1 = *(const short8v*)(wb + 16 * 64 * 8);
        short8v b2 = *(const short8v*)(wb + 2 * 16 * 64 * 8);
        short8v b3 = *(const short8v*)(wb + 3 * 16 * 64 * 8);
        acc0 = __builtin_amdgcn_mfma_f32_16x16x32_bf16(afrag, b0, acc0, 0, 0, 0);
        acc1 = __builtin_amdgcn_mfma_f32_16x16x32_bf16(afrag, b1, acc1, 0, 0, 0);
        acc2 = __builtin_amdgcn_mfma_f32_16x16x32_bf16(afrag, b2, acc2, 0, 0, 0);
        acc3 = __builtin_amdgcn_mfma_f32_16x16x32_bf16(afrag, b3, acc3, 0, 0, 0);
    }

#pragma unroll
    for (int t = 0; t < 4; ++t) {
        f32x4 acc = (t == 0) ? acc0 : (t == 1) ? acc1 : (t == 2) ? acc2 : acc3;
        int col = cb * 64 + t * 16 + (lane & 15);
        float bv = bias[col];
#pragma unroll
        for (int i = 0; i < 4; ++i) {
            int row = m0 + kgrp * 4 + i;
            if (row < N_NODES) out[(size_t)row * NOUT + col] = acc[i] + bv;
        }
    }
}

// ---------------- launcher ----------------

extern "C" void kernel_launch(void* const* d_in, const int* in_sizes, int n_in,
                              void* d_out, int out_size, void* d_ws, size_t ws_size,
                              hipStream_t stream) {
    const float* x    = (const float*)d_in[0];
    const float* vals = (const float*)d_in[1];
    const float* W    = (const float*)d_in[2];
    const float* b    = (const float*)d_in[3];
    const int*   rows = (const int*)d_in[4];
    const int*   cols = (const int*)d_in[5];
    float* out = (float*)d_out;

    char* ws = (char*)d_ws;
    size_t off = 0;
    auto alloc = [&](size_t bytes) -> void* {
        void* p = ws + off;
        off = (off + bytes + 255) & ~(size_t)255;
        return p;
    };
    ushort_t* Xb   = (ushort_t*)alloc(sizeof(ushort_t) * (size_t)N_NODES * FEAT);
    ushort_t* T1   = (ushort_t*)alloc(sizeof(ushort_t) * (size_t)N_NODES * FEAT);
    ushort_t* T2   = (ushort_t*)alloc(sizeof(ushort_t) * (size_t)N_NODES * FEAT);
    ushort_t* T3   = (ushort_t*)alloc(sizeof(ushort_t) * (size_t)N_NODES * FEAT);
    int*   row_ptr = (int*)alloc(sizeof(int) * (N_NODES + 1));
    int*   gcnt    = (int*)alloc(sizeof(int) * NBUCK);
    int*   bbase   = (int*)alloc(sizeof(int) * (NBUCK + 1));
    int*   gfill   = (int*)alloc(sizeof(int) * NBUCK);
    int2*  bpairs  = (int2*)alloc(sizeof(int2) * (size_t)N_EDGES);
    int2*  epairs  = (int2*)alloc(sizeof(int2) * (size_t)N_EDGES);
    ushort_t* wfrag = (ushort_t*)alloc(sizeof(ushort_t) * 8 * 16 * 64 * 8);

    // bucketed CSR build
    k_zero_int<<<1, 256, 0, stream>>>(gcnt, NBUCK);
    k_bhist<<<NTILE, 256, 0, stream>>>(rows, gcnt);
    k_bscan<<<1, 64, 0, stream>>>(gcnt, bbase, gfill);
    k_bucketA<<<NTILE, 256, 0, stream>>>(rows, cols, vals, gfill, bpairs);
    k_bucketB<<<NBUCK, 256, 0, stream>>>(bbase, bpairs, row_ptr, epairs);

    // dense-side prep
    k_xconv<<<(N_NODES * FEAT / 4 + 255) / 256, 256, 0, stream>>>(x, Xb);
    k_wprep<<<32, 256, 0, stream>>>(W, wfrag);

    // Chebyshev recurrence (bf16 storage, fp32 accumulate)
    k_spmm<0><<<N_NODES / 4, 256, 0, stream>>>(Xb, row_ptr, epairs, nullptr, T1);
    k_spmm<1><<<N_NODES / 4, 256, 0, stream>>>(T1, row_ptr, epairs, Xb, T2);
    k_spmm<1><<<N_NODES / 4, 256, 0, stream>>>(T2, row_ptr, epairs, T1, T3);

    // One fused MFMA GEMM: out = [Xb|T1|T2|T3] @ W + b
    dim3 grid((N_NODES + 63) / 64, 2);
    k_mfma_gemm<<<grid, 256, 0, stream>>>(Xb, T1, T2, T3, wfrag, b, out);
}

// Round 5
// 184.460 us; speedup vs baseline: 2.7448x; 1.1477x over previous
//
#include <hip/hip_runtime.h>

#define N_NODES 50000
#define N_EDGES 800000
#define FEAT    128
#define NOUT    128
#define NBUCK   196                        // ceil(50000/256)
#define NTILE   ((N_EDGES + 2047) / 2048)  // 391 phase-A blocks

typedef __attribute__((ext_vector_type(8))) short short8v;
typedef __attribute__((ext_vector_type(4))) float f32x4;
typedef __attribute__((ext_vector_type(2))) float f32x2;
typedef unsigned short ushort_t;
typedef unsigned char uchar_t;

#if defined(__has_builtin)
#if __has_builtin(__builtin_amdgcn_cvt_pk_f32_fp8) && __has_builtin(__builtin_amdgcn_cvt_pk_fp8_f32)
#define FP8_HW 1
#endif
#endif

static __device__ __forceinline__ unsigned short f2bf(float f) {
    union { float f; unsigned int u; } c; c.f = f;
    unsigned int u = c.u;
    return (unsigned short)((u + 0x7fffu + ((u >> 16) & 1u)) >> 16);
}
static __device__ __forceinline__ float bf_lo(unsigned int u) {
    return __uint_as_float(u << 16);
}
static __device__ __forceinline__ float bf_hi(unsigned int u) {
    return __uint_as_float(u & 0xffff0000u);
}

// ---- fp8 e4m3fn (OCP) helpers: HW cvt if available, manual fallback ----

static __device__ __forceinline__ unsigned int f2fp8_manual(float f) {
    unsigned int u = __float_as_uint(f);
    unsigned int s = (u >> 24) & 0x80u;
    unsigned int au = u & 0x7fffffffu;
    unsigned int q;
    if (au >= 0x43e00000u) {            // >= 448 -> clamp
        q = 0x7eu;
    } else if (au >= 0x3c800000u) {     // normal range (>= 2^-6)
        unsigned int e = (au >> 23) - 120u;   // 1..15
        unsigned int m = (au >> 20) & 7u;
        q = (e << 3) | m;
        unsigned int rem = au & 0xfffffu;
        q += (rem > 0x80000u) || ((rem == 0x80000u) && (q & 1u));
    } else {                            // denorm
        float af = __uint_as_float(au);
        q = (unsigned int)__float2int_rn(af * 512.0f);
    }
    return s | q;
}
static __device__ __forceinline__ float fp8_to_f32_manual(unsigned int b) {
    unsigned int s = (b & 0x80u) << 24;
    unsigned int q = b & 0x7fu;
    float r;
    if (q >= 8u) r = __uint_as_float((q << 20) + 0x3c000000u);
    else         r = (float)q * 0x1p-9f;
    return __uint_as_float(__float_as_uint(r) | s);
}

static __device__ __forceinline__ void fp8x4_dec(unsigned int u, float* o) {
#ifdef FP8_HW
    f32x2 lo = __builtin_amdgcn_cvt_pk_f32_fp8(u, false);
    f32x2 hi = __builtin_amdgcn_cvt_pk_f32_fp8(u, true);
    o[0] = lo[0]; o[1] = lo[1]; o[2] = hi[0]; o[3] = hi[1];
#else
    o[0] = fp8_to_f32_manual(u & 0xff);
    o[1] = fp8_to_f32_manual((u >> 8) & 0xff);
    o[2] = fp8_to_f32_manual((u >> 16) & 0xff);
    o[3] = fp8_to_f32_manual(u >> 24);
#endif
}
static __device__ __forceinline__ unsigned int fp8x4_enc(float a, float b, float c, float d) {
#ifdef FP8_HW
    int r = __builtin_amdgcn_cvt_pk_fp8_f32(a, b, 0, false);
    r = __builtin_amdgcn_cvt_pk_fp8_f32(c, d, r, true);
    return (unsigned int)r;
#else
    return f2fp8_manual(a) | (f2fp8_manual(b) << 8) |
           (f2fp8_manual(c) << 16) | (f2fp8_manual(d) << 24);
#endif
}

// ---------------- bucketed CSR build ----------------

__global__ void k_zero_int(int* __restrict__ p, int n) {
    int i = blockIdx.x * blockDim.x + threadIdx.x;
    if (i < n) p[i] = 0;
}

__global__ __launch_bounds__(256) void k_bhist(const int* __restrict__ rows,
                                               int* __restrict__ gcnt) {
    __shared__ int h[NBUCK];
    for (int i = threadIdx.x; i < NBUCK; i += 256) h[i] = 0;
    __syncthreads();
    const int base = blockIdx.x * 2048;
#pragma unroll
    for (int k = 0; k < 8; ++k) {
        int e = base + k * 256 + threadIdx.x;
        if (e < N_EDGES) atomicAdd(&h[rows[e] >> 8], 1);
    }
    __syncthreads();
    for (int i = threadIdx.x; i < NBUCK; i += 256)
        if (h[i]) atomicAdd(&gcnt[i], h[i]);
}

__global__ void k_bscan(const int* __restrict__ gcnt, int* __restrict__ bbase,
                        int* __restrict__ gfill) {
    if (threadIdx.x == 0 && blockIdx.x == 0) {
        int run = 0;
        for (int i = 0; i < NBUCK; ++i) {
            bbase[i] = run; gfill[i] = run; run += gcnt[i];
        }
        bbase[NBUCK] = run;
    }
}

__global__ __launch_bounds__(256) void k_bucketA(
    const int* __restrict__ rows, const int* __restrict__ cols,
    const float* __restrict__ vals, int* __restrict__ gfill,
    int2* __restrict__ bpairs)
{
    __shared__ int h[NBUCK];
    __shared__ int off[NBUCK];
    __shared__ int cb[NBUCK];
    for (int i = threadIdx.x; i < NBUCK; i += 256) { h[i] = 0; off[i] = 0; }
    __syncthreads();
    const int base = blockIdx.x * 2048;
    int enc[8];
#pragma unroll
    for (int k = 0; k < 8; ++k) {
        int e = base + k * 256 + threadIdx.x;
        enc[k] = -1;
        if (e < N_EDGES) {
            int r = rows[e];
            enc[k] = (r >> 8) | ((r & 255) << 16);
            atomicAdd(&h[r >> 8], 1);
        }
    }
    __syncthreads();
    for (int i = threadIdx.x; i < NBUCK; i += 256)
        cb[i] = h[i] ? atomicAdd(&gfill[i], h[i]) : 0;
    __syncthreads();
#pragma unroll
    for (int k = 0; k < 8; ++k) {
        int e = base + k * 256 + threadIdx.x;
        if (e >= N_EDGES) continue;
        int bk = enc[k] & 0xffff;
        int rowlo = enc[k] >> 16;
        int p = cb[bk] + atomicAdd(&off[bk], 1);
        int2 pr;
        pr.x = (rowlo << 16) | cols[e];
        pr.y = __float_as_int(vals[e]);
        bpairs[p] = pr;
    }
}

__global__ __launch_bounds__(256) void k_bucketB(
    const int* __restrict__ bbase, const int2* __restrict__ bpairs,
    int* __restrict__ row_ptr, int2* __restrict__ epairs)
{
    __shared__ int hist[256];
    __shared__ int scan[256];
    __shared__ int fill[256];
    const int b = blockIdx.x;
    const int t = threadIdx.x;
    const int beg = bbase[b], end = bbase[b + 1];
    hist[t] = 0;
    __syncthreads();
    for (int j = beg + t; j < end; j += 256)
        atomicAdd(&hist[bpairs[j].x >> 16], 1);
    __syncthreads();
    int orig = hist[t];
    int val = orig;
    scan[t] = val;
    __syncthreads();
#pragma unroll
    for (int o = 1; o < 256; o <<= 1) {
        int y = (t >= o) ? scan[t - o] : 0;
        __syncthreads();
        val += y;
        scan[t] = val;
        __syncthreads();
    }
    const int rp = beg + (val - orig);
    const int gr = b * 256 + t;
    if (gr <= N_NODES) row_ptr[gr] = rp;
    fill[t] = rp;
    __syncthreads();
    for (int j = beg + t; j < end; j += 256) {
        int2 pk = bpairs[j];
        int rowlo = pk.x >> 16;
        int p = atomicAdd(&fill[rowlo], 1);
        int2 pr;
        pr.x = pk.x & 0xffff;   // col (fits 16 bits: N=50000)
        pr.y = pk.y;
        epairs[p] = pr;
    }
}

// ---------------- x -> bf16 + fp8 copies ----------------

__global__ __launch_bounds__(256) void k_xconv(const float* __restrict__ x,
                                               ushort_t* __restrict__ xb,
                                               uchar_t* __restrict__ xf8) {
    int i = blockIdx.x * 256 + threadIdx.x;     // 800000 threads, 8 floats each
    float4 f0 = *(const float4*)(x + (size_t)i * 8);
    float4 f1 = *(const float4*)(x + (size_t)i * 8 + 4);
    uint4 ob;
    ob.x = (unsigned int)f2bf(f0.x) | ((unsigned int)f2bf(f0.y) << 16);
    ob.y = (unsigned int)f2bf(f0.z) | ((unsigned int)f2bf(f0.w) << 16);
    ob.z = (unsigned int)f2bf(f1.x) | ((unsigned int)f2bf(f1.y) << 16);
    ob.w = (unsigned int)f2bf(f1.z) | ((unsigned int)f2bf(f1.w) << 16);
    *(uint4*)(xb + (size_t)i * 8) = ob;
    uint2 of;
    of.x = fp8x4_enc(f0.x, f0.y, f0.z, f0.w);
    of.y = fp8x4_enc(f1.x, f1.y, f1.z, f1.w);
    *(uint2*)(xf8 + (size_t)i * 8) = of;
}

// ---------------- SpMM: fp8 gather, fp32 accum, bf16(+fp8) store ----------------
// 4 rows per wave: 16-lane group per row, 8 feats/lane (dwordx2 fp8 gather).
// MODE 0: out = L@in ; MODE 1: out = 2*(L@in) - sub   (sub read as bf16)

template <int MODE, int WF8>
__global__ __launch_bounds__(256) void k_spmm(
    const uchar_t* __restrict__ inf8, const int* __restrict__ row_ptr,
    const int2* __restrict__ epairs, const ushort_t* __restrict__ sub,
    ushort_t* __restrict__ outb, uchar_t* __restrict__ outf8)
{
    const int lane = threadIdx.x & 63;
    const int wid  = threadIdx.x >> 6;
    const int li   = lane & 15;                     // feature slot
    const int r    = blockIdx.x * 16 + wid * 4 + (lane >> 4);
    const int beg = row_ptr[r];
    const int n   = row_ptr[r + 1] - beg;

    int nm = n;
    nm = max(nm, __shfl_xor(nm, 16));
    nm = max(nm, __shfl_xor(nm, 32));

    float a[8];
#pragma unroll
    for (int k = 0; k < 8; ++k) a[k] = 0.f;

    auto body = [&](int j) {
        bool act = j < n;
        int idx = act ? (beg + j) : 0;
        int2 p = epairs[idx];
        float v = act ? __int_as_float(p.y) : 0.f;
        uint2 u = *(const uint2*)(inf8 + ((size_t)p.x << 7) + (li << 3));
        float d[8];
        fp8x4_dec(u.x, d);
        fp8x4_dec(u.y, d + 4);
#pragma unroll
        for (int k = 0; k < 8; ++k) a[k] = fmaf(v, d[k], a[k]);
    };

    int j = 0;
    for (; j + 2 <= nm; j += 2) { body(j); body(j + 1); }
    if (j < nm) body(j);

    if (MODE == 1) {
        uint4 su = *(const uint4*)(sub + (size_t)r * FEAT + li * 8);
        a[0] = 2.f * a[0] - bf_lo(su.x);
        a[1] = 2.f * a[1] - bf_hi(su.x);
        a[2] = 2.f * a[2] - bf_lo(su.y);
        a[3] = 2.f * a[3] - bf_hi(su.y);
        a[4] = 2.f * a[4] - bf_lo(su.z);
        a[5] = 2.f * a[5] - bf_hi(su.z);
        a[6] = 2.f * a[6] - bf_lo(su.w);
        a[7] = 2.f * a[7] - bf_hi(su.w);
    }

    uint4 ob;
    ob.x = (unsigned int)f2bf(a[0]) | ((unsigned int)f2bf(a[1]) << 16);
    ob.y = (unsigned int)f2bf(a[2]) | ((unsigned int)f2bf(a[3]) << 16);
    ob.z = (unsigned int)f2bf(a[4]) | ((unsigned int)f2bf(a[5]) << 16);
    ob.w = (unsigned int)f2bf(a[6]) | ((unsigned int)f2bf(a[7]) << 16);
    *(uint4*)(outb + (size_t)r * FEAT + li * 8) = ob;
    if (WF8) {
        uint2 of;
        of.x = fp8x4_enc(a[0], a[1], a[2], a[3]);
        of.y = fp8x4_enc(a[4], a[5], a[6], a[7]);
        *(uint2*)(outf8 + (size_t)r * FEAT + li * 8) = of;
    }
}

// ---------------- W prep: fp32 [512][128] -> bf16 fragment-ordered ----------------

__global__ void k_wprep(const float* __restrict__ W, ushort_t* __restrict__ wf) {
    int i = blockIdx.x * 256 + threadIdx.x;   // 8*16*64 = 8192
    if (i >= 8 * 16 * 64) return;
    int lane = i & 63;
    int kk = (i >> 6) & 15;
    int ct = i >> 10;
    int col = ct * 16 + (lane & 15);
    int k0 = kk * 32 + (lane >> 4) * 8;
    short8v o;
#pragma unroll
    for (int j = 0; j < 8; ++j)
        o[j] = (short)f2bf(W[(size_t)(k0 + j) * NOUT + col]);
    *(short8v*)(wf + (size_t)i * 8) = o;
}

// ---------------- Fused MFMA GEMM: out = [Xb|T1|T2|T3] @ W + b ----------------

__global__ __launch_bounds__(256) void k_mfma_gemm(
    const ushort_t* __restrict__ t0, const ushort_t* __restrict__ t1,
    const ushort_t* __restrict__ t2, const ushort_t* __restrict__ t3,
    const ushort_t* __restrict__ wfrag,
    const float* __restrict__ bias, float* __restrict__ out)
{
    const int lane = threadIdx.x & 63;
    const int wid  = threadIdx.x >> 6;
    const int m0   = blockIdx.x * 64 + wid * 16;
    const int cb   = blockIdx.y;
    const int arow = m0 + (lane & 15);
    const int kgrp = lane >> 4;

    f32x4 acc0 = {0.f, 0.f, 0.f, 0.f};
    f32x4 acc1 = {0.f, 0.f, 0.f, 0.f};
    f32x4 acc2 = {0.f, 0.f, 0.f, 0.f};
    f32x4 acc3 = {0.f, 0.f, 0.f, 0.f};

    const ushort_t* tp[4] = {t0, t1, t2, t3};
    const bool rowok = (arow < N_NODES);

#pragma unroll
    for (int kk = 0; kk < 16; ++kk) {
        const int term = kk >> 2;
        const ushort_t* ap = tp[term];
        short8v afrag;
        if (rowok) {
            afrag = *(const short8v*)(ap + (size_t)arow * FEAT + (kk & 3) * 32 + kgrp * 8);
        } else {
            afrag = (short8v)0;
        }
        const ushort_t* wb =
            wfrag + ((size_t)((cb * 4 + 0) * 16 + kk) * 64 + lane) * 8;
        short8v b0 = *(const short8v*)(wb);
        short8v b1 = *(const short8v*)(wb + 16 * 64 * 8);
        short8v b2 = *(const short8v*)(wb + 2 * 16 * 64 * 8);
        short8v b3 = *(const short8v*)(wb + 3 * 16 * 64 * 8);
        acc0 = __builtin_amdgcn_mfma_f32_16x16x32_bf16(afrag, b0, acc0, 0, 0, 0);
        acc1 = __builtin_amdgcn_mfma_f32_16x16x32_bf16(afrag, b1, acc1, 0, 0, 0);
        acc2 = __builtin_amdgcn_mfma_f32_16x16x32_bf16(afrag, b2, acc2, 0, 0, 0);
        acc3 = __builtin_amdgcn_mfma_f32_16x16x32_bf16(afrag, b3, acc3, 0, 0, 0);
    }

#pragma unroll
    for (int t = 0; t < 4; ++t) {
        f32x4 acc = (t == 0) ? acc0 : (t == 1) ? acc1 : (t == 2) ? acc2 : acc3;
        int col = cb * 64 + t * 16 + (lane & 15);
        float bv = bias[col];
#pragma unroll
        for (int i = 0; i < 4; ++i) {
            int row = m0 + kgrp * 4 + i;
            if (row < N_NODES) out[(size_t)row * NOUT + col] = acc[i] + bv;
        }
    }
}

// ---------------- launcher ----------------

extern "C" void kernel_launch(void* const* d_in, const int* in_sizes, int n_in,
                              void* d_out, int out_size, void* d_ws, size_t ws_size,
                              hipStream_t stream) {
    const float* x    = (const float*)d_in[0];
    const float* vals = (const float*)d_in[1];
    const float* W    = (const float*)d_in[2];
    const float* b    = (const float*)d_in[3];
    const int*   rows = (const int*)d_in[4];
    const int*   cols = (const int*)d_in[5];
    float* out = (float*)d_out;

    char* ws = (char*)d_ws;
    size_t off = 0;
    auto alloc = [&](size_t bytes) -> void* {
        void* p = ws + off;
        off = (off + bytes + 255) & ~(size_t)255;
        return p;
    };
    ushort_t* Xb    = (ushort_t*)alloc(sizeof(ushort_t) * (size_t)N_NODES * FEAT);
    ushort_t* T1b   = (ushort_t*)alloc(sizeof(ushort_t) * (size_t)N_NODES * FEAT);
    ushort_t* T2b   = (ushort_t*)alloc(sizeof(ushort_t) * (size_t)N_NODES * FEAT);
    ushort_t* T3b   = (ushort_t*)alloc(sizeof(ushort_t) * (size_t)N_NODES * FEAT);
    uchar_t*  Xf8   = (uchar_t*)alloc(sizeof(uchar_t) * (size_t)N_NODES * FEAT);
    uchar_t*  T1f8  = (uchar_t*)alloc(sizeof(uchar_t) * (size_t)N_NODES * FEAT);
    uchar_t*  T2f8  = (uchar_t*)alloc(sizeof(uchar_t) * (size_t)N_NODES * FEAT);
    int*   row_ptr  = (int*)alloc(sizeof(int) * (N_NODES + 1));
    int*   gcnt     = (int*)alloc(sizeof(int) * NBUCK);
    int*   bbase    = (int*)alloc(sizeof(int) * (NBUCK + 1));
    int*   gfill    = (int*)alloc(sizeof(int) * NBUCK);
    int2*  bpairs   = (int2*)alloc(sizeof(int2) * (size_t)N_EDGES);
    int2*  epairs   = (int2*)alloc(sizeof(int2) * (size_t)N_EDGES);
    ushort_t* wfrag = (ushort_t*)alloc(sizeof(ushort_t) * 8 * 16 * 64 * 8);

    // bucketed CSR build
    k_zero_int<<<1, 256, 0, stream>>>(gcnt, NBUCK);
    k_bhist<<<NTILE, 256, 0, stream>>>(rows, gcnt);
    k_bscan<<<1, 64, 0, stream>>>(gcnt, bbase, gfill);
    k_bucketA<<<NTILE, 256, 0, stream>>>(rows, cols, vals, gfill, bpairs);
    k_bucketB<<<NBUCK, 256, 0, stream>>>(bbase, bpairs, row_ptr, epairs);

    // dense-side prep
    k_xconv<<<N_NODES * FEAT / 8 / 256, 256, 0, stream>>>(x, Xb, Xf8);
    k_wprep<<<32, 256, 0, stream>>>(W, wfrag);

    // Chebyshev recurrence: fp8 gather, fp32 accum, bf16(+fp8) store
    k_spmm<0, 1><<<N_NODES / 16, 256, 0, stream>>>(Xf8,  row_ptr, epairs, nullptr, T1b, T1f8);
    k_spmm<1, 1><<<N_NODES / 16, 256, 0, stream>>>(T1f8, row_ptr, epairs, Xb,      T2b, T2f8);
    k_spmm<1, 0><<<N_NODES / 16, 256, 0, stream>>>(T2f8, row_ptr, epairs, T1b,     T3b, nullptr);

    // One fused MFMA GEMM: out = [Xb|T1|T2|T3] @ W + b
    dim3 grid((N_NODES + 63) / 64, 2);
    k_mfma_gemm<<<grid, 256, 0, stream>>>(Xb, T1b, T2b, T3b, wfrag, b, out);
}